// Round 9
// baseline (432.901 us; speedup 1.0000x reference)
//
#include <hip/hip_runtime.h>
#include <hip/hip_cooperative_groups.h>
#include <math.h>

namespace cg = cooperative_groups;

#define VPTS 35
#define CIN1 7
#define CH1  16
#define CH2  64
#define DD   10
#define HHH  400
#define WWW  352
#define BN_EPS 1e-5f
#define NSTRIPE 8

// ---------------------------------------------------------------------------
// ws float layout (coop path):
// [0:2048)    ws1  : per-stats-block partials (<=64 blocks x 32)
// [2048:3072) red2p: 8 stripes x 128 (sum2[64], sumsq2[64])
// [3072:3392) fallback stats area
// [4096 .. 4096+64K)        E1buf
// [4096+64K .. 4096+128K)   E2buf
// [4096+128K .. 4096+129K)  FLbuf
// ---------------------------------------------------------------------------

// ============================ fused cooperative kernel =====================
// P1: blocks [0,Sb) stats1 partials (no atomics, per-block slot);
//     blocks [Sb,G) fill out4[0,f1); block G-1 also zeros red2p.
// sync
// P2: blocks [0,Hb) heavy wave-per-voxel pass (E1/E2/FL + striped BN2 atomics);
//     blocks [Hb,G) fill out4[f1,n4).
// sync
// P3: all blocks: BN2 finalize from stripes + scatter atomicAdd.
__global__ void __launch_bounds__(256, 4) k_fused(
    const float* __restrict__ feat, const int* __restrict__ coord,
    const float* __restrict__ w1, const float* __restrict__ b1,
    const float* __restrict__ g1, const float* __restrict__ be1,
    const float* __restrict__ w2, const float* __restrict__ b2,
    const float* __restrict__ g2, const float* __restrict__ be2,
    float* __restrict__ out, float* __restrict__ ws,
    int K, int KP, long n4, long f1, float invN) {
  cg::grid_group grid = cg::this_grid();
  float4* out4 = (float4*)out;
  float* ws1   = ws;          // per-block stats1 partials
  float* red2p = ws + 2048;   // striped BN2 partials
  float* E1buf = ws + 4096;
  float* E2buf = E1buf + (size_t)64 * K;
  float* FLbuf = E2buf + (size_t)64 * K;

  const int G  = gridDim.x;
  const int Sb = G >> 4;      // stats blocks
  const int Hb = G >> 1;      // heavy blocks
  const int t = threadIdx.x, lane = t & 63, w = t >> 6;

  __shared__ __align__(16) float fs_s[4][248];
  __shared__ __align__(16) float pw1_s[4][560];
  __shared__ __align__(16) float agg1_s[4][16];
  __shared__ float ss[2 * CH2];
  __shared__ float ls[2 * CH1];
  __shared__ float scsh2_s[2 * CH2];

  // ------------------------------- P1 --------------------------------------
  if (blockIdx.x < Sb) {
    // stats1: 4 threads per point, 4 channels per thread (~50 VGPR)
    int tp = blockIdx.x * 256 + t;
    int p0 = tp >> 2, cq = tp & 3;
    int pstride = Sb * 64;
    float w1q[CIN1][4], b1q[4], s[4], q[4];
#pragma unroll
    for (int j = 0; j < CIN1; ++j)
#pragma unroll
      for (int cc = 0; cc < 4; ++cc) w1q[j][cc] = w1[j * CH1 + cq * 4 + cc];
#pragma unroll
    for (int cc = 0; cc < 4; ++cc) {
      b1q[cc] = b1[cq * 4 + cc];
      s[cc] = 0.f; q[cc] = 0.f;
    }
    for (int p = p0; p < KP; p += pstride) {
      float x[CIN1];
#pragma unroll
      for (int j = 0; j < CIN1; ++j) x[j] = feat[(size_t)p * CIN1 + j];
#pragma unroll
      for (int cc = 0; cc < 4; ++cc) {
        float a = b1q[cc];
#pragma unroll
        for (int j = 0; j < CIN1; ++j) a = fmaf(x[j], w1q[j][cc], a);
        a = fmaxf(a, 0.f);
        s[cc] += a;
        q[cc] = fmaf(a, a, q[cc]);
      }
    }
    if (t < 2 * CH1) ls[t] = 0.f;
    __syncthreads();
#pragma unroll
    for (int cc = 0; cc < 4; ++cc) {
      atomicAdd(&ls[cq * 4 + cc], s[cc]);
      atomicAdd(&ls[CH1 + cq * 4 + cc], q[cc]);
    }
    __syncthreads();
    if (t < 2 * CH1) ws1[blockIdx.x * 32 + t] = ls[t];
  } else {
    if (blockIdx.x == G - 1) {
      for (int i = t; i < NSTRIPE * 2 * CH2; i += 256) red2p[i] = 0.f;
    }
    // fill [0, f1)
    float4 zv = make_float4(0.f, 0.f, 0.f, 0.f);
    long fb = G - Sb;
    long stride = fb * 256;
    for (long zi = (long)(blockIdx.x - Sb) * 256 + t; zi < f1; zi += stride)
      out4[zi] = zv;
  }
  grid.sync();

  // ------------------------------- P2 --------------------------------------
  if (blockIdx.x < Hb) {
    float* fs   = fs_s[w];
    float* pw1  = pw1_s[w];
    float* agg1 = agg1_s[w];
    int c1 = lane & 15;
    float r1s = 0.f, r1q = 0.f;
    for (int sIdx = 0; sIdx < Sb; ++sIdx) {
      r1s += ws1[sIdx * 32 + c1];
      r1q += ws1[sIdx * 32 + CH1 + c1];
    }
    float mean1 = r1s * invN;
    float var1  = r1q * invN - mean1 * mean1;
    float sc1   = g1[c1] * rsqrtf(var1 + BN_EPS);
    float sh1   = be1[c1] - mean1 * sc1;
    float b1c   = b1[c1];
    float w1r[CIN1];
#pragma unroll
    for (int j = 0; j < CIN1; ++j) w1r[j] = w1[j * CH1 + c1];
    float wcol[32];
#pragma unroll
    for (int i = 0; i < 32; ++i) wcol[i] = w2[i * CH2 + lane];
    float b2c = b2[lane];
    float sgn = (g2[lane] >= 0.f) ? 1.f : -1.f;

    float lsum = 0.f, lsq = 0.f;
    int waveg = blockIdx.x * 4 + w;
    int nwave = Hb * 4;
    for (int k = waveg; k < K; k += nwave) {
      for (int i = lane; i < VPTS * CIN1; i += 64)
        fs[i] = feat[(size_t)k * (VPTS * CIN1) + i];
      bool vbit = false;
      if (lane < VPTS) {
        float m = fs[lane * CIN1];
#pragma unroll
        for (int j = 1; j < CIN1; ++j) m = fmaxf(m, fs[lane * CIN1 + j]);
        vbit = (m != 0.f);
      }
      unsigned long long mbits = __ballot(vbit);
#pragma unroll
      for (int j = 0; j < 9; ++j) {
        int idx = lane + 64 * j;
        if (idx < VPTS * CH1) {
          int p = idx >> 4;
          float a = b1c;
#pragma unroll
          for (int jj = 0; jj < CIN1; ++jj)
            a = fmaf(fs[p * CIN1 + jj], w1r[jj], a);
          a = fmaxf(a, 0.f);
          pw1[idx] = fmaf(a, sc1, sh1);
        }
      }
      {
        int g = lane >> 4;
        float am = -INFINITY;
        for (int p = g; p < VPTS; p += 4) am = fmaxf(am, pw1[p * CH1 + c1]);
        am = fmaxf(am, __shfl_xor(am, 16));
        am = fmaxf(am, __shfl_xor(am, 32));
        if (lane < CH1) agg1[lane] = am;
      }
      float aggdot = 0.f;
      {
        const float4* a4 = (const float4*)agg1;
#pragma unroll
        for (int i = 0; i < 4; ++i) {
          float4 v = a4[i];
          aggdot = fmaf(v.x, wcol[16 + 4 * i + 0], aggdot);
          aggdot = fmaf(v.y, wcol[16 + 4 * i + 1], aggdot);
          aggdot = fmaf(v.z, wcol[16 + 4 * i + 2], aggdot);
          aggdot = fmaf(v.w, wcol[16 + 4 * i + 3], aggdot);
        }
      }
      float E1w = -INFINITY, E2w = -INFINITY;
      const float4* p4 = (const float4*)pw1;
      for (int p = 0; p < VPTS; ++p) {
        float4 v0 = p4[p * 4 + 0], v1 = p4[p * 4 + 1];
        float4 v2 = p4[p * 4 + 2], v3 = p4[p * 4 + 3];
        float low = 0.f;
        low = fmaf(v0.x, wcol[0], low);  low = fmaf(v0.y, wcol[1], low);
        low = fmaf(v0.z, wcol[2], low);  low = fmaf(v0.w, wcol[3], low);
        low = fmaf(v1.x, wcol[4], low);  low = fmaf(v1.y, wcol[5], low);
        low = fmaf(v1.z, wcol[6], low);  low = fmaf(v1.w, wcol[7], low);
        low = fmaf(v2.x, wcol[8], low);  low = fmaf(v2.y, wcol[9], low);
        low = fmaf(v2.z, wcol[10], low); low = fmaf(v2.w, wcol[11], low);
        low = fmaf(v3.x, wcol[12], low); low = fmaf(v3.y, wcol[13], low);
        low = fmaf(v3.z, wcol[14], low); low = fmaf(v3.w, wcol[15], low);
        bool valid = (mbits >> p) & 1ull;
        float m = valid ? 1.f : 0.f;
        float pw2 = fmaxf(fmaf(m, low + aggdot, b2c), 0.f);
        lsum += pw2;
        lsq = fmaf(pw2, pw2, lsq);
        float sp = sgn * pw2;
        E2w = fmaxf(E2w, sp);
        if (valid) E1w = fmaxf(E1w, sp);
      }
      E1buf[(size_t)k * 64 + lane] = E1w;
      E2buf[(size_t)k * 64 + lane] = E2w;
      if (lane == 0) FLbuf[k] = (float)__popcll(mbits);
    }
    if (t < 2 * CH2) ss[t] = 0.f;
    __syncthreads();
    atomicAdd(&ss[lane], lsum);
    atomicAdd(&ss[CH2 + lane], lsq);
    __syncthreads();
    if (t < 2 * CH2)
      atomicAdd(&red2p[(blockIdx.x & (NSTRIPE - 1)) * 2 * CH2 + t], ss[t]);
  } else {
    // fill [f1, n4)
    float4 zv = make_float4(0.f, 0.f, 0.f, 0.f);
    long fb = G - Hb;
    long stride = fb * 256;
    for (long zi = f1 + (long)(blockIdx.x - Hb) * 256 + t; zi < n4; zi += stride)
      out4[zi] = zv;
  }
  grid.sync();

  // ------------------------------- P3 --------------------------------------
  if (t < CH2) {
    float rs = 0.f, rq = 0.f;
#pragma unroll
    for (int sIdx = 0; sIdx < NSTRIPE; ++sIdx) {
      rs += red2p[sIdx * 2 * CH2 + t];
      rq += red2p[sIdx * 2 * CH2 + CH2 + t];
    }
    float mean = rs * invN;
    float var = rq * invN - mean * mean;
    float inv = rsqrtf(var + BN_EPS);
    float sc = g2[t] * inv;
    scsh2_s[t] = sc;
    scsh2_s[CH2 + t] = be2[t] - mean * sc;
  }
  __syncthreads();
  int tl = t & 127;
  int c = tl & 63;
  float sc = scsh2_s[c], sh = scsh2_s[CH2 + c];
  for (int k = blockIdx.x * 2 + (t >> 7); k < K; k += G * 2) {
    float nv = FLbuf[k];
    bool anyV = nv > 0.f;
    bool anyI = nv < (float)VPTS;
    float cand = -INFINITY;
    if (anyV) {
      float E = (tl < 64) ? E1buf[(size_t)k * 64 + c] : E2buf[(size_t)k * 64 + c];
      cand = fmaf(fabsf(sc), E, sh);
    }
    if (anyI) cand = fmaxf(cand, 0.f);
    int4 cc = *reinterpret_cast<const int4*>(coord + (size_t)k * 4);
    long vox = ((long)(cc.x * DD + cc.y) * HHH + cc.z) * WWW + cc.w;
    atomicAdd(&out[vox * (2 * CH2) + tl], cand);
  }
}

// ====================== fallback path: R7 kernels ==========================
__global__ void k_init(float* __restrict__ ws) {
  for (int i = threadIdx.x; i < 3392; i += blockDim.x) ws[i] = 0.f;
}

__global__ void __launch_bounds__(256) k_A(
    const float* __restrict__ feat,
    const float* __restrict__ w1, const float* __restrict__ b1,
    float* __restrict__ red1p, float4* __restrict__ out4, long zA, int KP) {
  float w[CIN1][CH1], bb[CH1];
#pragma unroll
  for (int i = 0; i < CIN1; ++i)
#pragma unroll
    for (int c = 0; c < CH1; ++c) w[i][c] = w1[i * CH1 + c];
#pragma unroll
  for (int c = 0; c < CH1; ++c) bb[c] = b1[c];
  float s[CH1], q[CH1];
#pragma unroll
  for (int c = 0; c < CH1; ++c) { s[c] = 0.f; q[c] = 0.f; }
  int tid = blockIdx.x * blockDim.x + threadIdx.x;
  int stride = gridDim.x * blockDim.x;
  for (int idx = tid; idx < KP; idx += stride) {
    float x[CIN1];
#pragma unroll
    for (int i = 0; i < CIN1; ++i) x[i] = feat[(size_t)idx * CIN1 + i];
#pragma unroll
    for (int c = 0; c < CH1; ++c) {
      float a = bb[c];
#pragma unroll
      for (int i = 0; i < CIN1; ++i) a = fmaf(x[i], w[i][c], a);
      a = fmaxf(a, 0.f);
      s[c] += a;
      q[c] = fmaf(a, a, q[c]);
    }
  }
  float4 z = make_float4(0.f, 0.f, 0.f, 0.f);
  for (long i = tid; i < zA; i += stride) out4[i] = z;
  __shared__ float ssum[2 * CH1];
  if (threadIdx.x < 2 * CH1) ssum[threadIdx.x] = 0.f;
  __syncthreads();
#pragma unroll
  for (int c = 0; c < CH1; ++c) {
    float a = s[c], b = q[c];
    for (int o = 32; o > 0; o >>= 1) {
      a += __shfl_down(a, o);
      b += __shfl_down(b, o);
    }
    if ((threadIdx.x & 63) == 0) {
      atomicAdd(&ssum[c], a);
      atomicAdd(&ssum[CH1 + c], b);
    }
  }
  __syncthreads();
  if (threadIdx.x < 2 * CH1)
    atomicAdd(&red1p[(blockIdx.x & (NSTRIPE - 1)) * 2 * CH1 + threadIdx.x],
              ssum[threadIdx.x]);
}

__global__ void __launch_bounds__(256) k_heavy_fb(
    const float* __restrict__ feat,
    const float* __restrict__ w1, const float* __restrict__ b1,
    const float* __restrict__ g1, const float* __restrict__ be1,
    const float* __restrict__ red1p,
    const float* __restrict__ w2, const float* __restrict__ b2,
    const float* __restrict__ g2,
    float* __restrict__ red2p,
    float* __restrict__ E1buf, float* __restrict__ E2buf,
    float* __restrict__ FLbuf, int K,
    float4* __restrict__ out4, long z0, long n4, float invN) {
  __shared__ __align__(16) float fs_s[4][248];
  __shared__ __align__(16) float pw1_s[4][560];
  __shared__ __align__(16) float agg1_s[4][16];
  __shared__ float ss[2 * CH2];
  int t = threadIdx.x, lane = t & 63, w = t >> 6;
  float* fs   = fs_s[w];
  float* pw1  = pw1_s[w];
  float* agg1 = agg1_s[w];
  int c1 = lane & 15;
  float r1s = 0.f, r1q = 0.f;
#pragma unroll
  for (int sIdx = 0; sIdx < NSTRIPE; ++sIdx) {
    r1s += red1p[sIdx * 2 * CH1 + c1];
    r1q += red1p[sIdx * 2 * CH1 + CH1 + c1];
  }
  float mean1 = r1s * invN;
  float var1  = r1q * invN - mean1 * mean1;
  float sc1   = g1[c1] * rsqrtf(var1 + BN_EPS);
  float sh1   = be1[c1] - mean1 * sc1;
  float b1c   = b1[c1];
  float w1r[CIN1];
#pragma unroll
  for (int j = 0; j < CIN1; ++j) w1r[j] = w1[j * CH1 + c1];
  float wcol[32];
#pragma unroll
  for (int i = 0; i < 32; ++i) wcol[i] = w2[i * CH2 + lane];
  float b2c = b2[lane];
  float sgn = (g2[lane] >= 0.f) ? 1.f : -1.f;
  float lsum = 0.f, lsq = 0.f;
  int waveg = blockIdx.x * 4 + w;
  int nwave = gridDim.x * 4;
  for (int k = waveg; k < K; k += nwave) {
    for (int i = lane; i < VPTS * CIN1; i += 64)
      fs[i] = feat[(size_t)k * (VPTS * CIN1) + i];
    bool vbit = false;
    if (lane < VPTS) {
      float m = fs[lane * CIN1];
#pragma unroll
      for (int j = 1; j < CIN1; ++j) m = fmaxf(m, fs[lane * CIN1 + j]);
      vbit = (m != 0.f);
    }
    unsigned long long mbits = __ballot(vbit);
#pragma unroll
    for (int j = 0; j < 9; ++j) {
      int idx = lane + 64 * j;
      if (idx < VPTS * CH1) {
        int p = idx >> 4;
        float a = b1c;
#pragma unroll
        for (int jj = 0; jj < CIN1; ++jj) a = fmaf(fs[p * CIN1 + jj], w1r[jj], a);
        a = fmaxf(a, 0.f);
        pw1[idx] = fmaf(a, sc1, sh1);
      }
    }
    {
      int g = lane >> 4;
      float am = -INFINITY;
      for (int p = g; p < VPTS; p += 4) am = fmaxf(am, pw1[p * CH1 + c1]);
      am = fmaxf(am, __shfl_xor(am, 16));
      am = fmaxf(am, __shfl_xor(am, 32));
      if (lane < CH1) agg1[lane] = am;
    }
    float aggdot = 0.f;
    {
      const float4* a4 = (const float4*)agg1;
#pragma unroll
      for (int i = 0; i < 4; ++i) {
        float4 v = a4[i];
        aggdot = fmaf(v.x, wcol[16 + 4 * i + 0], aggdot);
        aggdot = fmaf(v.y, wcol[16 + 4 * i + 1], aggdot);
        aggdot = fmaf(v.z, wcol[16 + 4 * i + 2], aggdot);
        aggdot = fmaf(v.w, wcol[16 + 4 * i + 3], aggdot);
      }
    }
    float E1w = -INFINITY, E2w = -INFINITY;
    const float4* p4 = (const float4*)pw1;
    for (int p = 0; p < VPTS; ++p) {
      float4 v0 = p4[p * 4 + 0], v1 = p4[p * 4 + 1];
      float4 v2 = p4[p * 4 + 2], v3 = p4[p * 4 + 3];
      float low = 0.f;
      low = fmaf(v0.x, wcol[0], low);  low = fmaf(v0.y, wcol[1], low);
      low = fmaf(v0.z, wcol[2], low);  low = fmaf(v0.w, wcol[3], low);
      low = fmaf(v1.x, wcol[4], low);  low = fmaf(v1.y, wcol[5], low);
      low = fmaf(v1.z, wcol[6], low);  low = fmaf(v1.w, wcol[7], low);
      low = fmaf(v2.x, wcol[8], low);  low = fmaf(v2.y, wcol[9], low);
      low = fmaf(v2.z, wcol[10], low); low = fmaf(v2.w, wcol[11], low);
      low = fmaf(v3.x, wcol[12], low); low = fmaf(v3.y, wcol[13], low);
      low = fmaf(v3.z, wcol[14], low); low = fmaf(v3.w, wcol[15], low);
      bool valid = (mbits >> p) & 1ull;
      float m = valid ? 1.f : 0.f;
      float pw2 = fmaxf(fmaf(m, low + aggdot, b2c), 0.f);
      lsum += pw2;
      lsq = fmaf(pw2, pw2, lsq);
      float sp = sgn * pw2;
      E2w = fmaxf(E2w, sp);
      if (valid) E1w = fmaxf(E1w, sp);
    }
    E1buf[(size_t)k * 64 + lane] = E1w;
    E2buf[(size_t)k * 64 + lane] = E2w;
    if (lane == 0) FLbuf[k] = (float)__popcll(mbits);
  }
  {
    float4 zv = make_float4(0.f, 0.f, 0.f, 0.f);
    long stride = (long)gridDim.x * 256;
    for (long zi = z0 + (long)blockIdx.x * 256 + t; zi < n4; zi += stride)
      out4[zi] = zv;
  }
  if (t < 2 * CH2) ss[t] = 0.f;
  __syncthreads();
  atomicAdd(&ss[lane], lsum);
  atomicAdd(&ss[CH2 + lane], lsq);
  __syncthreads();
  if (t < 2 * CH2)
    atomicAdd(&red2p[(blockIdx.x & (NSTRIPE - 1)) * 2 * CH2 + t], ss[t]);
}

__global__ void __launch_bounds__(256) k_scatter_fb(
    const float* __restrict__ E1buf, const float* __restrict__ E2buf,
    const float* __restrict__ FLbuf, const float* __restrict__ red2p,
    const float* __restrict__ g2, const float* __restrict__ be2,
    const int* __restrict__ coord, float* __restrict__ out, int K,
    float invN) {
  __shared__ float scsh2_s[2 * CH2];
  int t = threadIdx.x;
  if (t < CH2) {
    float rs = 0.f, rq = 0.f;
#pragma unroll
    for (int sIdx = 0; sIdx < NSTRIPE; ++sIdx) {
      rs += red2p[sIdx * 2 * CH2 + t];
      rq += red2p[sIdx * 2 * CH2 + CH2 + t];
    }
    float mean = rs * invN;
    float var = rq * invN - mean * mean;
    float inv = rsqrtf(var + BN_EPS);
    float sc = g2[t] * inv;
    scsh2_s[t] = sc;
    scsh2_s[CH2 + t] = be2[t] - mean * sc;
  }
  __syncthreads();
  int k = blockIdx.x * 2 + (t >> 7);
  if (k >= K) return;
  int tl = t & 127;
  int c = tl & 63;
  float nv = FLbuf[k];
  bool anyV = nv > 0.f;
  bool anyI = nv < (float)VPTS;
  float sc = scsh2_s[c], sh = scsh2_s[CH2 + c];
  float cand = -INFINITY;
  if (anyV) {
    float E = (tl < 64) ? E1buf[(size_t)k * 64 + c] : E2buf[(size_t)k * 64 + c];
    cand = fmaf(fabsf(sc), E, sh);
  }
  if (anyI) cand = fmaxf(cand, 0.f);
  int4 cc = *reinterpret_cast<const int4*>(coord + (size_t)k * 4);
  long vox = ((long)(cc.x * DD + cc.y) * HHH + cc.z) * WWW + cc.w;
  atomicAdd(&out[vox * (2 * CH2) + tl], cand);
}

extern "C" void kernel_launch(void* const* d_in, const int* in_sizes, int n_in,
                              void* d_out, int out_size, void* d_ws, size_t ws_size,
                              hipStream_t stream) {
  const float* feat = (const float*)d_in[0];
  const int* coord  = (const int*)d_in[1];
  const float* w1  = (const float*)d_in[3];
  const float* b1  = (const float*)d_in[4];
  const float* g1  = (const float*)d_in[5];
  const float* be1 = (const float*)d_in[6];
  const float* w2  = (const float*)d_in[7];
  const float* b2  = (const float*)d_in[8];
  const float* g2  = (const float*)d_in[9];
  const float* be2 = (const float*)d_in[10];
  float* out = (float*)d_out;
  float* ws = (float*)d_ws;

  int K = in_sizes[0] / (VPTS * CIN1);
  int KP = K * VPTS;
  float invN = 1.f / (float)KP;

  size_t need_bytes = (4096 + (size_t)K * 129) * sizeof(float);
  long n4 = (long)out_size / 4;
  long f1 = (n4 * 3) / 10;  // 30% fill in P1, 70% in P2

  bool done = false;
  if (ws_size >= need_bytes) {
    int maxB = 0;
    hipError_t oe = hipOccupancyMaxActiveBlocksPerMultiprocessor(
        &maxB, k_fused, 256, 0);
    if (oe == hipSuccess && maxB >= 1) {
      int G = maxB * 256;
      if (G > 1024) G = 1024;
      if (G >= 64) {
        void* args[] = {(void*)&feat, (void*)&coord, (void*)&w1, (void*)&b1,
                        (void*)&g1, (void*)&be1, (void*)&w2, (void*)&b2,
                        (void*)&g2, (void*)&be2, (void*)&out, (void*)&ws,
                        (void*)&K, (void*)&KP, (void*)&n4, (void*)&f1,
                        (void*)&invN};
        hipError_t le = hipLaunchCooperativeKernel(
            (const void*)k_fused, dim3(G), dim3(256), args, 0, stream);
        if (le == hipSuccess) done = true;
      }
    }
  }
  if (!done && ws_size >= need_bytes) {
    // R7 fallback (proven 194us path), reusing coop ws layout offsets
    float* red1p = ws;          // reuse ws1 area for striped red1 (256 floats)
    float* red2p = ws + 2048;
    float* E1buf = ws + 4096;
    float* E2buf = E1buf + (size_t)64 * K;
    float* FLbuf = E2buf + (size_t)64 * K;
    long zA = (n4 * 55) / 100;
    k_init<<<1, 1024, 0, stream>>>(ws);
    k_A<<<2048, 256, 0, stream>>>(feat, w1, b1, red1p, (float4*)out, zA, KP);
    k_heavy_fb<<<2048, 256, 0, stream>>>(feat, w1, b1, g1, be1, red1p,
                                         w2, b2, g2, red2p, E1buf, E2buf,
                                         FLbuf, K, (float4*)out, zA, n4, invN);
    k_scatter_fb<<<(K + 1) / 2, 256, 0, stream>>>(E1buf, E2buf, FLbuf, red2p,
                                                  g2, be2, coord, out, K, invN);
  }
}

// Round 10
// 251.675 us; speedup vs baseline: 1.7201x; 1.7201x over previous
//
#include <hip/hip_runtime.h>
#include <math.h>

#define VPTS 35
#define CIN1 7
#define CH1  16
#define CH2  64
#define DD   10
#define HHH  400
#define WWW  352
#define BN_EPS 1e-5f
#define NSTRIPE 8

// ---------------------------------------------------------------------------
// ws float layout (main path):
// [0:256)     red1p  : 8 stripes x 32  (sum1[16], sumsq1[16])
// [256:1280)  red2p  : 8 stripes x 128 (sum2[64], sumsq2[64])
// [1280:1600) fallback stats area (red1 32, scsh1 32, red2 128, scsh2 128)
// [2048 .. 2048+64K)        E1buf (per-voxel signed extreme, valid pts)
// [2048+64K .. 2048+128K)   E2buf (per-voxel signed extreme, all pts)
// [2048+128K .. 2048+129K)  FLbuf (per-voxel valid count)
// ---------------------------------------------------------------------------

__global__ void k_init(float* __restrict__ ws) {
  for (int i = threadIdx.x; i < 1280; i += blockDim.x) ws[i] = 0.f;
}

// Stats1 (register accum, striped atomics) + zero the first zA float4s of out.
// All loads precede all stores per wave -> no vmcnt drain hazard.
__global__ void __launch_bounds__(256) k_A(
    const float* __restrict__ feat,
    const float* __restrict__ w1, const float* __restrict__ b1,
    float* __restrict__ red1p, float4* __restrict__ out4, long zA, int KP) {
  float w[CIN1][CH1], bb[CH1];
#pragma unroll
  for (int i = 0; i < CIN1; ++i)
#pragma unroll
    for (int c = 0; c < CH1; ++c) w[i][c] = w1[i * CH1 + c];
#pragma unroll
  for (int c = 0; c < CH1; ++c) bb[c] = b1[c];
  float s[CH1], q[CH1];
#pragma unroll
  for (int c = 0; c < CH1; ++c) { s[c] = 0.f; q[c] = 0.f; }
  int tid = blockIdx.x * blockDim.x + threadIdx.x;
  int stride = gridDim.x * blockDim.x;
  for (int idx = tid; idx < KP; idx += stride) {
    float x[CIN1];
#pragma unroll
    for (int i = 0; i < CIN1; ++i) x[i] = feat[(size_t)idx * CIN1 + i];
#pragma unroll
    for (int c = 0; c < CH1; ++c) {
      float a = bb[c];
#pragma unroll
      for (int i = 0; i < CIN1; ++i) a = fmaf(x[i], w[i][c], a);
      a = fmaxf(a, 0.f);
      s[c] += a;
      q[c] = fmaf(a, a, q[c]);
    }
  }
  float4 z = make_float4(0.f, 0.f, 0.f, 0.f);
  for (long i = tid; i < zA; i += stride) out4[i] = z;
  __shared__ float ssum[2 * CH1];
  if (threadIdx.x < 2 * CH1) ssum[threadIdx.x] = 0.f;
  __syncthreads();
#pragma unroll
  for (int c = 0; c < CH1; ++c) {
    float a = s[c], b = q[c];
    for (int o = 32; o > 0; o >>= 1) {
      a += __shfl_down(a, o);
      b += __shfl_down(b, o);
    }
    if ((threadIdx.x & 63) == 0) {
      atomicAdd(&ssum[c], a);
      atomicAdd(&ssum[CH1 + c], b);
    }
  }
  __syncthreads();
  if (threadIdx.x < 2 * CH1)
    atomicAdd(&red1p[(blockIdx.x & (NSTRIPE - 1)) * 2 * CH1 + threadIdx.x],
              ssum[threadIdx.x]);
}

// Heavy pass with INTERLEAVED role-split: role = blockIdx & 3.
// role != 0 (3 of 4 blocks): pure streaming zero-fill of out4[z0,n4) -- no
//   loads, no waits, saturates the HBM write queue.
// role == 0 (1 of 4 blocks): wave-per-voxel compute, no bulk stores, its
//   vmcnt waits cover only its own feat loads.
// Interleaved indices keep both roles CO-RESIDENT on every CU at all times
// (R8's contiguous ranges ran fill first, then compute -- no overlap).
__global__ void __launch_bounds__(256) k_heavy(
    const float* __restrict__ feat,
    const float* __restrict__ w1, const float* __restrict__ b1,
    const float* __restrict__ g1, const float* __restrict__ be1,
    const float* __restrict__ red1p,
    const float* __restrict__ w2, const float* __restrict__ b2,
    const float* __restrict__ g2,
    float* __restrict__ red2p,
    float* __restrict__ E1buf, float* __restrict__ E2buf,
    float* __restrict__ FLbuf, int K,
    float4* __restrict__ out4, long z0, long n4, float invN) {
  int t = threadIdx.x, lane = t & 63, w = t >> 6;
  int role = blockIdx.x & 3;
  if (role != 0) {
    // ---- fill role ----
    float4 zv = make_float4(0.f, 0.f, 0.f, 0.f);
    long nfill = (long)(gridDim.x >> 2) * 3;
    long fidx  = (long)(blockIdx.x >> 2) * 3 + (role - 1);
    long stride = nfill * 256;
    for (long zi = z0 + fidx * 256 + t; zi < n4; zi += stride)
      out4[zi] = zv;
    return;
  }
  // ---- compute role ----
  __shared__ __align__(16) float fs_s[4][248];
  __shared__ __align__(16) float pw1_s[4][560];   // [35][16] per wave
  __shared__ __align__(16) float agg1_s[4][16];
  __shared__ float ss[2 * CH2];
  float* fs   = fs_s[w];
  float* pw1  = pw1_s[w];
  float* agg1 = agg1_s[w];
  int cb = blockIdx.x >> 2;
  int ncb = gridDim.x >> 2;

  // Per-lane constants. c1 = lane&15 (pw1 idx = lane + 64j keeps low 4 bits).
  int c1 = lane & 15;
  float r1s = 0.f, r1q = 0.f;
#pragma unroll
  for (int sIdx = 0; sIdx < NSTRIPE; ++sIdx) {
    r1s += red1p[sIdx * 2 * CH1 + c1];
    r1q += red1p[sIdx * 2 * CH1 + CH1 + c1];
  }
  float mean1 = r1s * invN;
  float var1  = r1q * invN - mean1 * mean1;
  float sc1   = g1[c1] * rsqrtf(var1 + BN_EPS);
  float sh1   = be1[c1] - mean1 * sc1;
  float b1c   = b1[c1];
  float w1r[CIN1];
#pragma unroll
  for (int j = 0; j < CIN1; ++j) w1r[j] = w1[j * CH1 + c1];
  float wcol[32];
#pragma unroll
  for (int i = 0; i < 32; ++i) wcol[i] = w2[i * CH2 + lane];
  float b2c = b2[lane];
  float sgn = (g2[lane] >= 0.f) ? 1.f : -1.f;

  float lsum = 0.f, lsq = 0.f;
  int waveg = cb * 4 + w;
  int nwave = ncb * 4;
  for (int k = waveg; k < K; k += nwave) {
    // stage fs (wave-coalesced)
    for (int i = lane; i < VPTS * CIN1; i += 64)
      fs[i] = feat[(size_t)k * (VPTS * CIN1) + i];
    // mask ballot
    bool vbit = false;
    if (lane < VPTS) {
      float m = fs[lane * CIN1];
#pragma unroll
      for (int j = 1; j < CIN1; ++j) m = fmaxf(m, fs[lane * CIN1 + j]);
      vbit = (m != 0.f);
    }
    unsigned long long mbits = __ballot(vbit);
    // pw1 (BN'd, raw/unmasked)
#pragma unroll
    for (int j = 0; j < 9; ++j) {
      int idx = lane + 64 * j;
      if (idx < VPTS * CH1) {
        int p = idx >> 4;
        float a = b1c;
#pragma unroll
        for (int jj = 0; jj < CIN1; ++jj) a = fmaf(fs[p * CIN1 + jj], w1r[jj], a);
        a = fmaxf(a, 0.f);
        pw1[idx] = fmaf(a, sc1, sh1);
      }
    }
    // agg1
    {
      int g = lane >> 4;
      float am = -INFINITY;
      for (int p = g; p < VPTS; p += 4) am = fmaxf(am, pw1[p * CH1 + c1]);
      am = fmaxf(am, __shfl_xor(am, 16));
      am = fmaxf(am, __shfl_xor(am, 32));
      if (lane < CH1) agg1[lane] = am;
    }
    // aggdot for this lane's c2
    float aggdot = 0.f;
    {
      const float4* a4 = (const float4*)agg1;
#pragma unroll
      for (int i = 0; i < 4; ++i) {
        float4 v = a4[i];
        aggdot = fmaf(v.x, wcol[16 + 4 * i + 0], aggdot);
        aggdot = fmaf(v.y, wcol[16 + 4 * i + 1], aggdot);
        aggdot = fmaf(v.z, wcol[16 + 4 * i + 2], aggdot);
        aggdot = fmaf(v.w, wcol[16 + 4 * i + 3], aggdot);
      }
    }
    // stage 2: broadcast pw1 rows; stats + signed extremes in registers
    float E1w = -INFINITY, E2w = -INFINITY;
    const float4* p4 = (const float4*)pw1;
    for (int p = 0; p < VPTS; ++p) {
      float4 v0 = p4[p * 4 + 0], v1 = p4[p * 4 + 1];
      float4 v2 = p4[p * 4 + 2], v3 = p4[p * 4 + 3];
      float low = 0.f;
      low = fmaf(v0.x, wcol[0], low);  low = fmaf(v0.y, wcol[1], low);
      low = fmaf(v0.z, wcol[2], low);  low = fmaf(v0.w, wcol[3], low);
      low = fmaf(v1.x, wcol[4], low);  low = fmaf(v1.y, wcol[5], low);
      low = fmaf(v1.z, wcol[6], low);  low = fmaf(v1.w, wcol[7], low);
      low = fmaf(v2.x, wcol[8], low);  low = fmaf(v2.y, wcol[9], low);
      low = fmaf(v2.z, wcol[10], low); low = fmaf(v2.w, wcol[11], low);
      low = fmaf(v3.x, wcol[12], low); low = fmaf(v3.y, wcol[13], low);
      low = fmaf(v3.z, wcol[14], low); low = fmaf(v3.w, wcol[15], low);
      bool valid = (mbits >> p) & 1ull;
      float m = valid ? 1.f : 0.f;
      float pw2 = fmaxf(fmaf(m, low + aggdot, b2c), 0.f);
      lsum += pw2;
      lsq = fmaf(pw2, pw2, lsq);
      float sp = sgn * pw2;
      E2w = fmaxf(E2w, sp);
      if (valid) E1w = fmaxf(E1w, sp);
    }
    E1buf[(size_t)k * 64 + lane] = E1w;
    E2buf[(size_t)k * 64 + lane] = E2w;
    if (lane == 0) FLbuf[k] = (float)__popcll(mbits);
  }
  // BN2 block reduce -> striped global atomics
  if (t < 2 * CH2) ss[t] = 0.f;
  __syncthreads();
  atomicAdd(&ss[lane], lsum);
  atomicAdd(&ss[CH2 + lane], lsq);
  __syncthreads();
  if (t < 2 * CH2)
    atomicAdd(&red2p[(cb & (NSTRIPE - 1)) * 2 * CH2 + t], ss[t]);
}

// Scatter: BN2 finalize (striped partials summed); apply affine to extremes,
// combine with the mask-zero candidate, atomicAdd into the dense grid.
__global__ void __launch_bounds__(256) k_scatter(
    const float* __restrict__ E1buf, const float* __restrict__ E2buf,
    const float* __restrict__ FLbuf, const float* __restrict__ red2p,
    const float* __restrict__ g2, const float* __restrict__ be2,
    const int* __restrict__ coord, float* __restrict__ out, int K,
    float invN) {
  __shared__ float scsh2_s[2 * CH2];
  int t = threadIdx.x;
  if (t < CH2) {
    float rs = 0.f, rq = 0.f;
#pragma unroll
    for (int sIdx = 0; sIdx < NSTRIPE; ++sIdx) {
      rs += red2p[sIdx * 2 * CH2 + t];
      rq += red2p[sIdx * 2 * CH2 + CH2 + t];
    }
    float mean = rs * invN;
    float var = rq * invN - mean * mean;
    float inv = rsqrtf(var + BN_EPS);
    float sc = g2[t] * inv;
    scsh2_s[t] = sc;
    scsh2_s[CH2 + t] = be2[t] - mean * sc;
  }
  __syncthreads();
  int k = blockIdx.x * 2 + (t >> 7);
  if (k >= K) return;
  int tl = t & 127;
  int c = tl & 63;
  float nv = FLbuf[k];
  bool anyV = nv > 0.f;
  bool anyI = nv < (float)VPTS;
  float sc = scsh2_s[c], sh = scsh2_s[CH2 + c];
  float cand = -INFINITY;
  if (anyV) {
    float E = (tl < 64) ? E1buf[(size_t)k * 64 + c] : E2buf[(size_t)k * 64 + c];
    cand = fmaf(fabsf(sc), E, sh);
  }
  if (anyI) cand = fmaxf(cand, 0.f);
  int4 cc = *reinterpret_cast<const int4*>(coord + (size_t)k * 4);
  long vox = ((long)(cc.x * DD + cc.y) * HHH + cc.z) * WWW + cc.w;
  atomicAdd(&out[vox * (2 * CH2) + tl], cand);
}

// ------------------- fallback path (ws too small): R3/R4 kernels -----------
__global__ void __launch_bounds__(256) k_zero(float4* __restrict__ out4,
                                              long n4, float* __restrict__ wsfb) {
  long i = (long)blockIdx.x * blockDim.x + threadIdx.x;
  long stride = (long)gridDim.x * blockDim.x;
  float4 z = make_float4(0.f, 0.f, 0.f, 0.f);
  for (; i < n4; i += stride) out4[i] = z;
  if (blockIdx.x == 0 && threadIdx.x < 320) wsfb[threadIdx.x] = 0.f;
}

__global__ void k_finalize(const float* __restrict__ red,
                           const float* __restrict__ g,
                           const float* __restrict__ be,
                           float* __restrict__ scsh, int CH, float invN) {
  int c = threadIdx.x;
  if (c < CH) {
    float mean = red[c] * invN;
    float var = red[CH + c] * invN - mean * mean;
    float inv = rsqrtf(var + BN_EPS);
    float sc = g[c] * inv;
    scsh[c] = sc;
    scsh[CH + c] = be[c] - mean * sc;
  }
}

__global__ void __launch_bounds__(256) k_stats1_fb(
    const float* __restrict__ feat,
    const float* __restrict__ w1, const float* __restrict__ b1,
    float* __restrict__ red1, int KP) {
  float w[CIN1][CH1], bb[CH1];
#pragma unroll
  for (int i = 0; i < CIN1; ++i)
#pragma unroll
    for (int c = 0; c < CH1; ++c) w[i][c] = w1[i * CH1 + c];
#pragma unroll
  for (int c = 0; c < CH1; ++c) bb[c] = b1[c];
  float s[CH1], q[CH1];
#pragma unroll
  for (int c = 0; c < CH1; ++c) { s[c] = 0.f; q[c] = 0.f; }
  int tid = blockIdx.x * blockDim.x + threadIdx.x;
  int stride = gridDim.x * blockDim.x;
  for (int idx = tid; idx < KP; idx += stride) {
    float x[CIN1];
#pragma unroll
    for (int i = 0; i < CIN1; ++i) x[i] = feat[(size_t)idx * CIN1 + i];
#pragma unroll
    for (int c = 0; c < CH1; ++c) {
      float a = bb[c];
#pragma unroll
      for (int i = 0; i < CIN1; ++i) a = fmaf(x[i], w[i][c], a);
      a = fmaxf(a, 0.f);
      s[c] += a;
      q[c] = fmaf(a, a, q[c]);
    }
  }
  __shared__ float ssum[2 * CH1];
  if (threadIdx.x < 2 * CH1) ssum[threadIdx.x] = 0.f;
  __syncthreads();
#pragma unroll
  for (int c = 0; c < CH1; ++c) {
    float a = s[c], b = q[c];
    for (int o = 32; o > 0; o >>= 1) {
      a += __shfl_down(a, o);
      b += __shfl_down(b, o);
    }
    if ((threadIdx.x & 63) == 0) {
      atomicAdd(&ssum[c], a);
      atomicAdd(&ssum[CH1 + c], b);
    }
  }
  __syncthreads();
  if (threadIdx.x < 2 * CH1) atomicAdd(&red1[threadIdx.x], ssum[threadIdx.x]);
}

__device__ __forceinline__ void compute_x2_old(
    const float* __restrict__ feat, int k, int t,
    const float* __restrict__ w1, const float* __restrict__ b1,
    const float* __restrict__ scsh1,
    float* fs, float* mask_s, float* pw1_s, float* agg1_s, float* x2_s) {
  if (t < VPTS * CIN1) fs[t] = feat[(size_t)k * (VPTS * CIN1) + t];
  __syncthreads();
  if (t < VPTS) {
    float m = fs[t * CIN1];
#pragma unroll
    for (int i = 1; i < CIN1; ++i) m = fmaxf(m, fs[t * CIN1 + i]);
    mask_s[t] = (m != 0.f) ? 1.f : 0.f;
  }
  for (int i = t; i < VPTS * CH1; i += 256) {
    int p = i >> 4, c = i & 15;
    float acc = b1[c];
#pragma unroll
    for (int j = 0; j < CIN1; ++j) acc = fmaf(fs[p * CIN1 + j], w1[j * CH1 + c], acc);
    acc = fmaxf(acc, 0.f);
    pw1_s[i] = fmaf(acc, scsh1[c], scsh1[CH1 + c]);
  }
  __syncthreads();
  if (t < CH1) {
    float m = pw1_s[t];
    for (int p = 1; p < VPTS; ++p) m = fmaxf(m, pw1_s[p * CH1 + t]);
    agg1_s[t] = m;
  }
  __syncthreads();
  for (int i = t; i < VPTS * 32; i += 256) {
    int p = i >> 5, c = i & 31;
    x2_s[i] = (c < CH1 ? pw1_s[p * CH1 + c] : agg1_s[c - CH1]) * mask_s[p];
  }
  __syncthreads();
}

__global__ void __launch_bounds__(256) k_stats2_old(
    const float* __restrict__ feat,
    const float* __restrict__ w1, const float* __restrict__ b1,
    const float* __restrict__ scsh1,
    const float* __restrict__ w2, const float* __restrict__ b2,
    float* __restrict__ red2, int K) {
  __shared__ float fs[VPTS * CIN1], mask_s[VPTS], pw1_s[VPTS * CH1], agg1_s[CH1];
  __shared__ __align__(16) float x2_s[VPTS * 32];
  __shared__ __align__(16) float w2_s[32 * CH2];
  __shared__ float ss[2 * CH2];
  int t = threadIdx.x;
  for (int i = t; i < 32 * CH2; i += 256) w2_s[i] = w2[i];
  if (t < 2 * CH2) ss[t] = 0.f;
  __syncthreads();
  int c = t & 63;
  float wcol[32];
#pragma unroll
  for (int i = 0; i < 32; ++i) wcol[i] = w2_s[i * CH2 + c];
  float bb = b2[c];
  float lsum = 0.f, lsq = 0.f;
  for (int k = blockIdx.x; k < K; k += gridDim.x) {
    compute_x2_old(feat, k, t, w1, b1, scsh1, fs, mask_s, pw1_s, agg1_s, x2_s);
    for (int p = t >> 6; p < VPTS; p += 4) {
      const float4* xv = (const float4*)(x2_s + p * 32);
      float a = bb;
#pragma unroll
      for (int i = 0; i < 8; ++i) {
        float4 v = xv[i];
        a = fmaf(v.x, wcol[4 * i + 0], a);
        a = fmaf(v.y, wcol[4 * i + 1], a);
        a = fmaf(v.z, wcol[4 * i + 2], a);
        a = fmaf(v.w, wcol[4 * i + 3], a);
      }
      a = fmaxf(a, 0.f);
      lsum += a;
      lsq = fmaf(a, a, lsq);
    }
  }
  atomicAdd(&ss[c], lsum);
  atomicAdd(&ss[CH2 + c], lsq);
  __syncthreads();
  if (t < 2 * CH2) atomicAdd(&red2[t], ss[t]);
}

__global__ void __launch_bounds__(256) k_final_old(
    const float* __restrict__ feat,
    const float* __restrict__ w1, const float* __restrict__ b1,
    const float* __restrict__ scsh1,
    const float* __restrict__ w2, const float* __restrict__ b2,
    const float* __restrict__ scsh2,
    const int* __restrict__ coord,
    float* __restrict__ out, int K) {
  __shared__ float fs[VPTS * CIN1], mask_s[VPTS], pw1_s[VPTS * CH1], agg1_s[CH1];
  __shared__ __align__(16) float x2_s[VPTS * 32];
  __shared__ __align__(16) float w2_s[32 * CH2];
  __shared__ float pw2_s[VPTS * CH2];
  __shared__ float agg2_s[CH2];
  int t = threadIdx.x;
  for (int i = t; i < 32 * CH2; i += 256) w2_s[i] = w2[i];
  __syncthreads();
  int c = t & 63;
  float wcol[32];
#pragma unroll
  for (int i = 0; i < 32; ++i) wcol[i] = w2_s[i * CH2 + c];
  float bb = b2[c];
  float sc = scsh2[c], sh = scsh2[CH2 + c];
  for (int k = blockIdx.x; k < K; k += gridDim.x) {
    compute_x2_old(feat, k, t, w1, b1, scsh1, fs, mask_s, pw1_s, agg1_s, x2_s);
    for (int p = t >> 6; p < VPTS; p += 4) {
      const float4* xv = (const float4*)(x2_s + p * 32);
      float a = bb;
#pragma unroll
      for (int i = 0; i < 8; ++i) {
        float4 v = xv[i];
        a = fmaf(v.x, wcol[4 * i + 0], a);
        a = fmaf(v.y, wcol[4 * i + 1], a);
        a = fmaf(v.z, wcol[4 * i + 2], a);
        a = fmaf(v.w, wcol[4 * i + 3], a);
      }
      a = fmaxf(a, 0.f);
      pw2_s[p * CH2 + c] = fmaf(a, sc, sh);
    }
    __syncthreads();
    if (t < CH2) {
      float m = pw2_s[t];
      for (int p = 1; p < VPTS; ++p) m = fmaxf(m, pw2_s[p * CH2 + t]);
      agg2_s[t] = m;
    }
    __syncthreads();
    if (t < 2 * CH2) {
      float vm = -INFINITY;
      if (t < CH2) {
        for (int p = 0; p < VPTS; ++p) vm = fmaxf(vm, pw2_s[p * CH2 + t] * mask_s[p]);
      } else {
        float a = agg2_s[t - CH2];
        for (int p = 0; p < VPTS; ++p) vm = fmaxf(vm, a * mask_s[p]);
      }
      int4 cc = *reinterpret_cast<const int4*>(coord + (size_t)k * 4);
      long vox = ((long)(cc.x * DD + cc.y) * HHH + cc.z) * WWW + cc.w;
      atomicAdd(&out[vox * (2 * CH2) + t], vm);
    }
  }
}

extern "C" void kernel_launch(void* const* d_in, const int* in_sizes, int n_in,
                              void* d_out, int out_size, void* d_ws, size_t ws_size,
                              hipStream_t stream) {
  const float* feat = (const float*)d_in[0];
  const int* coord  = (const int*)d_in[1];
  const float* w1  = (const float*)d_in[3];
  const float* b1  = (const float*)d_in[4];
  const float* g1  = (const float*)d_in[5];
  const float* be1 = (const float*)d_in[6];
  const float* w2  = (const float*)d_in[7];
  const float* b2  = (const float*)d_in[8];
  const float* g2  = (const float*)d_in[9];
  const float* be2 = (const float*)d_in[10];
  float* out = (float*)d_out;
  float* ws = (float*)d_ws;

  int K = in_sizes[0] / (VPTS * CIN1);
  int KP = K * VPTS;
  float invN = 1.f / (float)KP;

  float* red1p = ws;          // 256
  float* red2p = ws + 256;    // 1024
  float* fb    = ws + 1280;   // 320 (fallback stats area)
  float* E1buf = ws + 2048;
  float* E2buf = E1buf + (size_t)64 * K;
  float* FLbuf = E2buf + (size_t)64 * K;

  size_t need_bytes = (2048 + (size_t)K * 129) * sizeof(float);

  long n4 = (long)out_size / 4;
  long zA = (n4 * 40) / 100;  // 40% fill in k_A, 60% in k_heavy fill-role

  if (ws_size >= need_bytes) {
    k_init<<<1, 1024, 0, stream>>>(ws);
    k_A<<<2048, 256, 0, stream>>>(feat, w1, b1, red1p, (float4*)out, zA, KP);
    k_heavy<<<2048, 256, 0, stream>>>(feat, w1, b1, g1, be1, red1p,
                                      w2, b2, g2, red2p, E1buf, E2buf, FLbuf, K,
                                      (float4*)out, zA, n4, invN);
    k_scatter<<<(K + 1) / 2, 256, 0, stream>>>(E1buf, E2buf, FLbuf, red2p,
                                               g2, be2, coord, out, K, invN);
  } else {
    float* red1  = fb;
    float* scsh1 = fb + 32;
    float* red2  = fb + 64;
    float* scsh2 = fb + 192;
    k_zero<<<2048, 256, 0, stream>>>((float4*)out, n4, fb);
    k_stats1_fb<<<512, 256, 0, stream>>>(feat, w1, b1, red1, KP);
    k_finalize<<<1, 64, 0, stream>>>(red1, g1, be1, scsh1, CH1, invN);
    k_stats2_old<<<1024, 256, 0, stream>>>(feat, w1, b1, scsh1, w2, b2, red2, K);
    k_finalize<<<1, 64, 0, stream>>>(red2, g2, be2, scsh2, CH2, invN);
    k_final_old<<<2048, 256, 0, stream>>>(feat, w1, b1, scsh1, w2, b2, scsh2,
                                          coord, out, K);
  }
}

// Round 11
// 187.047 us; speedup vs baseline: 2.3144x; 1.3455x over previous
//
#include <hip/hip_runtime.h>
#include <math.h>

#define VPTS 35
#define CIN1 7
#define CH1  16
#define CH2  64
#define DD   10
#define HHH  400
#define WWW  352
#define BN_EPS 1e-5f
#define NSTRIPE 8

// ---------------------------------------------------------------------------
// ws float layout (main path):
// [0:256)     red1p  : 8 stripes x 32  (sum1[16], sumsq1[16])
// [256:1280)  red2p  : 8 stripes x 128 (sum2[64], sumsq2[64])
// [1280:1600) fallback stats area (red1 32, scsh1 32, red2 128, scsh2 128)
// [2048 .. 2048+64K)        E1buf (per-voxel signed extreme, valid pts)
// [2048+64K .. 2048+128K)   E2buf (per-voxel signed extreme, all pts)
// [2048+128K .. 2048+129K)  FLbuf (per-voxel valid count)
//
// Structure (R11): CLEAN SEPARATION. All overlap schemes (R6-R10) lost to
// plain serial phases because the rocclr memset fill sustains 6.6-6.8 TB/s
// while any fill mixed into a compute kernel runs slower AND serializes.
//   memset(out 721MB ~107us) -> memset(ws) -> stats1(8us) -> heavy(~28us)
//   -> scatter(~12us)
// ---------------------------------------------------------------------------

// Stats1: persistent, register accumulation, striped atomics (depth 512/8).
__global__ void __launch_bounds__(256) k_stats1(
    const float* __restrict__ feat,
    const float* __restrict__ w1, const float* __restrict__ b1,
    float* __restrict__ red1p, int KP) {
  float w[CIN1][CH1], bb[CH1];
#pragma unroll
  for (int i = 0; i < CIN1; ++i)
#pragma unroll
    for (int c = 0; c < CH1; ++c) w[i][c] = w1[i * CH1 + c];
#pragma unroll
  for (int c = 0; c < CH1; ++c) bb[c] = b1[c];
  float s[CH1], q[CH1];
#pragma unroll
  for (int c = 0; c < CH1; ++c) { s[c] = 0.f; q[c] = 0.f; }
  int tid = blockIdx.x * blockDim.x + threadIdx.x;
  int stride = gridDim.x * blockDim.x;
  for (int idx = tid; idx < KP; idx += stride) {
    float x[CIN1];
#pragma unroll
    for (int i = 0; i < CIN1; ++i) x[i] = feat[(size_t)idx * CIN1 + i];
#pragma unroll
    for (int c = 0; c < CH1; ++c) {
      float a = bb[c];
#pragma unroll
      for (int i = 0; i < CIN1; ++i) a = fmaf(x[i], w[i][c], a);
      a = fmaxf(a, 0.f);
      s[c] += a;
      q[c] = fmaf(a, a, q[c]);
    }
  }
  __shared__ float ssum[2 * CH1];
  if (threadIdx.x < 2 * CH1) ssum[threadIdx.x] = 0.f;
  __syncthreads();
#pragma unroll
  for (int c = 0; c < CH1; ++c) {
    float a = s[c], b = q[c];
    for (int o = 32; o > 0; o >>= 1) {
      a += __shfl_down(a, o);
      b += __shfl_down(b, o);
    }
    if ((threadIdx.x & 63) == 0) {
      atomicAdd(&ssum[c], a);
      atomicAdd(&ssum[CH1 + c], b);
    }
  }
  __syncthreads();
  if (threadIdx.x < 2 * CH1)
    atomicAdd(&red1p[(blockIdx.x & (NSTRIPE - 1)) * 2 * CH1 + threadIdx.x],
              ssum[threadIdx.x]);
}

// Heavy pass, WAVE-PER-VOXEL, compute only (no fill). Barrier-free voxel
// loop (wave-synchronous LDS). lane = output channel c2; mask in ballot;
// BN2 stats + per-voxel signed extremes in registers; striped BN2 atomics.
__global__ void __launch_bounds__(256) k_heavy(
    const float* __restrict__ feat,
    const float* __restrict__ w1, const float* __restrict__ b1,
    const float* __restrict__ g1, const float* __restrict__ be1,
    const float* __restrict__ red1p,
    const float* __restrict__ w2, const float* __restrict__ b2,
    const float* __restrict__ g2,
    float* __restrict__ red2p,
    float* __restrict__ E1buf, float* __restrict__ E2buf,
    float* __restrict__ FLbuf, int K, float invN) {
  __shared__ __align__(16) float fs_s[4][248];
  __shared__ __align__(16) float pw1_s[4][560];   // [35][16] per wave
  __shared__ __align__(16) float agg1_s[4][16];
  __shared__ float ss[2 * CH2];
  int t = threadIdx.x, lane = t & 63, w = t >> 6;
  float* fs   = fs_s[w];
  float* pw1  = pw1_s[w];
  float* agg1 = agg1_s[w];

  // Per-lane constants. c1 = lane&15 (pw1 idx = lane + 64j keeps low 4 bits).
  int c1 = lane & 15;
  float r1s = 0.f, r1q = 0.f;
#pragma unroll
  for (int sIdx = 0; sIdx < NSTRIPE; ++sIdx) {
    r1s += red1p[sIdx * 2 * CH1 + c1];
    r1q += red1p[sIdx * 2 * CH1 + CH1 + c1];
  }
  float mean1 = r1s * invN;
  float var1  = r1q * invN - mean1 * mean1;
  float sc1   = g1[c1] * rsqrtf(var1 + BN_EPS);
  float sh1   = be1[c1] - mean1 * sc1;
  float b1c   = b1[c1];
  float w1r[CIN1];
#pragma unroll
  for (int j = 0; j < CIN1; ++j) w1r[j] = w1[j * CH1 + c1];
  float wcol[32];
#pragma unroll
  for (int i = 0; i < 32; ++i) wcol[i] = w2[i * CH2 + lane];
  float b2c = b2[lane];
  float sgn = (g2[lane] >= 0.f) ? 1.f : -1.f;

  float lsum = 0.f, lsq = 0.f;
  int waveg = blockIdx.x * 4 + w;
  int nwave = gridDim.x * 4;
  for (int k = waveg; k < K; k += nwave) {
    // stage fs (wave-coalesced)
    for (int i = lane; i < VPTS * CIN1; i += 64)
      fs[i] = feat[(size_t)k * (VPTS * CIN1) + i];
    // mask ballot
    bool vbit = false;
    if (lane < VPTS) {
      float m = fs[lane * CIN1];
#pragma unroll
      for (int j = 1; j < CIN1; ++j) m = fmaxf(m, fs[lane * CIN1 + j]);
      vbit = (m != 0.f);
    }
    unsigned long long mbits = __ballot(vbit);
    // pw1 (BN'd, raw/unmasked)
#pragma unroll
    for (int j = 0; j < 9; ++j) {
      int idx = lane + 64 * j;
      if (idx < VPTS * CH1) {
        int p = idx >> 4;
        float a = b1c;
#pragma unroll
        for (int jj = 0; jj < CIN1; ++jj) a = fmaf(fs[p * CIN1 + jj], w1r[jj], a);
        a = fmaxf(a, 0.f);
        pw1[idx] = fmaf(a, sc1, sh1);
      }
    }
    // agg1
    {
      int g = lane >> 4;
      float am = -INFINITY;
      for (int p = g; p < VPTS; p += 4) am = fmaxf(am, pw1[p * CH1 + c1]);
      am = fmaxf(am, __shfl_xor(am, 16));
      am = fmaxf(am, __shfl_xor(am, 32));
      if (lane < CH1) agg1[lane] = am;
    }
    // aggdot for this lane's c2
    float aggdot = 0.f;
    {
      const float4* a4 = (const float4*)agg1;
#pragma unroll
      for (int i = 0; i < 4; ++i) {
        float4 v = a4[i];
        aggdot = fmaf(v.x, wcol[16 + 4 * i + 0], aggdot);
        aggdot = fmaf(v.y, wcol[16 + 4 * i + 1], aggdot);
        aggdot = fmaf(v.z, wcol[16 + 4 * i + 2], aggdot);
        aggdot = fmaf(v.w, wcol[16 + 4 * i + 3], aggdot);
      }
    }
    // stage 2: broadcast pw1 rows; stats + signed extremes in registers
    float E1w = -INFINITY, E2w = -INFINITY;
    const float4* p4 = (const float4*)pw1;
    for (int p = 0; p < VPTS; ++p) {
      float4 v0 = p4[p * 4 + 0], v1 = p4[p * 4 + 1];
      float4 v2 = p4[p * 4 + 2], v3 = p4[p * 4 + 3];
      float low = 0.f;
      low = fmaf(v0.x, wcol[0], low);  low = fmaf(v0.y, wcol[1], low);
      low = fmaf(v0.z, wcol[2], low);  low = fmaf(v0.w, wcol[3], low);
      low = fmaf(v1.x, wcol[4], low);  low = fmaf(v1.y, wcol[5], low);
      low = fmaf(v1.z, wcol[6], low);  low = fmaf(v1.w, wcol[7], low);
      low = fmaf(v2.x, wcol[8], low);  low = fmaf(v2.y, wcol[9], low);
      low = fmaf(v2.z, wcol[10], low); low = fmaf(v2.w, wcol[11], low);
      low = fmaf(v3.x, wcol[12], low); low = fmaf(v3.y, wcol[13], low);
      low = fmaf(v3.z, wcol[14], low); low = fmaf(v3.w, wcol[15], low);
      bool valid = (mbits >> p) & 1ull;
      float m = valid ? 1.f : 0.f;
      float pw2 = fmaxf(fmaf(m, low + aggdot, b2c), 0.f);
      lsum += pw2;
      lsq = fmaf(pw2, pw2, lsq);
      float sp = sgn * pw2;
      E2w = fmaxf(E2w, sp);
      if (valid) E1w = fmaxf(E1w, sp);
    }
    E1buf[(size_t)k * 64 + lane] = E1w;
    E2buf[(size_t)k * 64 + lane] = E2w;
    if (lane == 0) FLbuf[k] = (float)__popcll(mbits);
  }
  // BN2 block reduce -> striped global atomics
  if (t < 2 * CH2) ss[t] = 0.f;
  __syncthreads();
  atomicAdd(&ss[lane], lsum);
  atomicAdd(&ss[CH2 + lane], lsq);
  __syncthreads();
  if (t < 2 * CH2)
    atomicAdd(&red2p[(blockIdx.x & (NSTRIPE - 1)) * 2 * CH2 + t], ss[t]);
}

// Scatter: BN2 finalize (striped partials summed); apply affine to extremes,
// combine with the mask-zero candidate, atomicAdd into the dense grid.
__global__ void __launch_bounds__(256) k_scatter(
    const float* __restrict__ E1buf, const float* __restrict__ E2buf,
    const float* __restrict__ FLbuf, const float* __restrict__ red2p,
    const float* __restrict__ g2, const float* __restrict__ be2,
    const int* __restrict__ coord, float* __restrict__ out, int K,
    float invN) {
  __shared__ float scsh2_s[2 * CH2];
  int t = threadIdx.x;
  if (t < CH2) {
    float rs = 0.f, rq = 0.f;
#pragma unroll
    for (int sIdx = 0; sIdx < NSTRIPE; ++sIdx) {
      rs += red2p[sIdx * 2 * CH2 + t];
      rq += red2p[sIdx * 2 * CH2 + CH2 + t];
    }
    float mean = rs * invN;
    float var = rq * invN - mean * mean;
    float inv = rsqrtf(var + BN_EPS);
    float sc = g2[t] * inv;
    scsh2_s[t] = sc;
    scsh2_s[CH2 + t] = be2[t] - mean * sc;
  }
  __syncthreads();
  int k = blockIdx.x * 2 + (t >> 7);
  if (k >= K) return;
  int tl = t & 127;
  int c = tl & 63;
  float nv = FLbuf[k];
  bool anyV = nv > 0.f;
  bool anyI = nv < (float)VPTS;
  float sc = scsh2_s[c], sh = scsh2_s[CH2 + c];
  float cand = -INFINITY;
  if (anyV) {
    float E = (tl < 64) ? E1buf[(size_t)k * 64 + c] : E2buf[(size_t)k * 64 + c];
    cand = fmaf(fabsf(sc), E, sh);
  }
  if (anyI) cand = fmaxf(cand, 0.f);
  int4 cc = *reinterpret_cast<const int4*>(coord + (size_t)k * 4);
  long vox = ((long)(cc.x * DD + cc.y) * HHH + cc.z) * WWW + cc.w;
  atomicAdd(&out[vox * (2 * CH2) + tl], cand);
}

// ------------------- fallback path (ws too small): R3/R4 kernels -----------
__global__ void k_finalize(const float* __restrict__ red,
                           const float* __restrict__ g,
                           const float* __restrict__ be,
                           float* __restrict__ scsh, int CH, float invN) {
  int c = threadIdx.x;
  if (c < CH) {
    float mean = red[c] * invN;
    float var = red[CH + c] * invN - mean * mean;
    float inv = rsqrtf(var + BN_EPS);
    float sc = g[c] * inv;
    scsh[c] = sc;
    scsh[CH + c] = be[c] - mean * sc;
  }
}

__global__ void __launch_bounds__(256) k_stats1_fb(
    const float* __restrict__ feat,
    const float* __restrict__ w1, const float* __restrict__ b1,
    float* __restrict__ red1, int KP) {
  float w[CIN1][CH1], bb[CH1];
#pragma unroll
  for (int i = 0; i < CIN1; ++i)
#pragma unroll
    for (int c = 0; c < CH1; ++c) w[i][c] = w1[i * CH1 + c];
#pragma unroll
  for (int c = 0; c < CH1; ++c) bb[c] = b1[c];
  float s[CH1], q[CH1];
#pragma unroll
  for (int c = 0; c < CH1; ++c) { s[c] = 0.f; q[c] = 0.f; }
  int tid = blockIdx.x * blockDim.x + threadIdx.x;
  int stride = gridDim.x * blockDim.x;
  for (int idx = tid; idx < KP; idx += stride) {
    float x[CIN1];
#pragma unroll
    for (int i = 0; i < CIN1; ++i) x[i] = feat[(size_t)idx * CIN1 + i];
#pragma unroll
    for (int c = 0; c < CH1; ++c) {
      float a = bb[c];
#pragma unroll
      for (int i = 0; i < CIN1; ++i) a = fmaf(x[i], w[i][c], a);
      a = fmaxf(a, 0.f);
      s[c] += a;
      q[c] = fmaf(a, a, q[c]);
    }
  }
  __shared__ float ssum[2 * CH1];
  if (threadIdx.x < 2 * CH1) ssum[threadIdx.x] = 0.f;
  __syncthreads();
#pragma unroll
  for (int c = 0; c < CH1; ++c) {
    float a = s[c], b = q[c];
    for (int o = 32; o > 0; o >>= 1) {
      a += __shfl_down(a, o);
      b += __shfl_down(b, o);
    }
    if ((threadIdx.x & 63) == 0) {
      atomicAdd(&ssum[c], a);
      atomicAdd(&ssum[CH1 + c], b);
    }
  }
  __syncthreads();
  if (threadIdx.x < 2 * CH1) atomicAdd(&red1[threadIdx.x], ssum[threadIdx.x]);
}

__device__ __forceinline__ void compute_x2_old(
    const float* __restrict__ feat, int k, int t,
    const float* __restrict__ w1, const float* __restrict__ b1,
    const float* __restrict__ scsh1,
    float* fs, float* mask_s, float* pw1_s, float* agg1_s, float* x2_s) {
  if (t < VPTS * CIN1) fs[t] = feat[(size_t)k * (VPTS * CIN1) + t];
  __syncthreads();
  if (t < VPTS) {
    float m = fs[t * CIN1];
#pragma unroll
    for (int i = 1; i < CIN1; ++i) m = fmaxf(m, fs[t * CIN1 + i]);
    mask_s[t] = (m != 0.f) ? 1.f : 0.f;
  }
  for (int i = t; i < VPTS * CH1; i += 256) {
    int p = i >> 4, c = i & 15;
    float acc = b1[c];
#pragma unroll
    for (int j = 0; j < CIN1; ++j) acc = fmaf(fs[p * CIN1 + j], w1[j * CH1 + c], acc);
    acc = fmaxf(acc, 0.f);
    pw1_s[i] = fmaf(acc, scsh1[c], scsh1[CH1 + c]);
  }
  __syncthreads();
  if (t < CH1) {
    float m = pw1_s[t];
    for (int p = 1; p < VPTS; ++p) m = fmaxf(m, pw1_s[p * CH1 + t]);
    agg1_s[t] = m;
  }
  __syncthreads();
  for (int i = t; i < VPTS * 32; i += 256) {
    int p = i >> 5, c = i & 31;
    x2_s[i] = (c < CH1 ? pw1_s[p * CH1 + c] : agg1_s[c - CH1]) * mask_s[p];
  }
  __syncthreads();
}

__global__ void __launch_bounds__(256) k_stats2_old(
    const float* __restrict__ feat,
    const float* __restrict__ w1, const float* __restrict__ b1,
    const float* __restrict__ scsh1,
    const float* __restrict__ w2, const float* __restrict__ b2,
    float* __restrict__ red2, int K) {
  __shared__ float fs[VPTS * CIN1], mask_s[VPTS], pw1_s[VPTS * CH1], agg1_s[CH1];
  __shared__ __align__(16) float x2_s[VPTS * 32];
  __shared__ __align__(16) float w2_s[32 * CH2];
  __shared__ float ss[2 * CH2];
  int t = threadIdx.x;
  for (int i = t; i < 32 * CH2; i += 256) w2_s[i] = w2[i];
  if (t < 2 * CH2) ss[t] = 0.f;
  __syncthreads();
  int c = t & 63;
  float wcol[32];
#pragma unroll
  for (int i = 0; i < 32; ++i) wcol[i] = w2_s[i * CH2 + c];
  float bb = b2[c];
  float lsum = 0.f, lsq = 0.f;
  for (int k = blockIdx.x; k < K; k += gridDim.x) {
    compute_x2_old(feat, k, t, w1, b1, scsh1, fs, mask_s, pw1_s, agg1_s, x2_s);
    for (int p = t >> 6; p < VPTS; p += 4) {
      const float4* xv = (const float4*)(x2_s + p * 32);
      float a = bb;
#pragma unroll
      for (int i = 0; i < 8; ++i) {
        float4 v = xv[i];
        a = fmaf(v.x, wcol[4 * i + 0], a);
        a = fmaf(v.y, wcol[4 * i + 1], a);
        a = fmaf(v.z, wcol[4 * i + 2], a);
        a = fmaf(v.w, wcol[4 * i + 3], a);
      }
      a = fmaxf(a, 0.f);
      lsum += a;
      lsq = fmaf(a, a, lsq);
    }
  }
  atomicAdd(&ss[c], lsum);
  atomicAdd(&ss[CH2 + c], lsq);
  __syncthreads();
  if (t < 2 * CH2) atomicAdd(&red2[t], ss[t]);
}

__global__ void __launch_bounds__(256) k_final_old(
    const float* __restrict__ feat,
    const float* __restrict__ w1, const float* __restrict__ b1,
    const float* __restrict__ scsh1,
    const float* __restrict__ w2, const float* __restrict__ b2,
    const float* __restrict__ scsh2,
    const int* __restrict__ coord,
    float* __restrict__ out, int K) {
  __shared__ float fs[VPTS * CIN1], mask_s[VPTS], pw1_s[VPTS * CH1], agg1_s[CH1];
  __shared__ __align__(16) float x2_s[VPTS * 32];
  __shared__ __align__(16) float w2_s[32 * CH2];
  __shared__ float pw2_s[VPTS * CH2];
  __shared__ float agg2_s[CH2];
  int t = threadIdx.x;
  for (int i = t; i < 32 * CH2; i += 256) w2_s[i] = w2[i];
  __syncthreads();
  int c = t & 63;
  float wcol[32];
#pragma unroll
  for (int i = 0; i < 32; ++i) wcol[i] = w2_s[i * CH2 + c];
  float bb = b2[c];
  float sc = scsh2[c], sh = scsh2[CH2 + c];
  for (int k = blockIdx.x; k < K; k += gridDim.x) {
    compute_x2_old(feat, k, t, w1, b1, scsh1, fs, mask_s, pw1_s, agg1_s, x2_s);
    for (int p = t >> 6; p < VPTS; p += 4) {
      const float4* xv = (const float4*)(x2_s + p * 32);
      float a = bb;
#pragma unroll
      for (int i = 0; i < 8; ++i) {
        float4 v = xv[i];
        a = fmaf(v.x, wcol[4 * i + 0], a);
        a = fmaf(v.y, wcol[4 * i + 1], a);
        a = fmaf(v.z, wcol[4 * i + 2], a);
        a = fmaf(v.w, wcol[4 * i + 3], a);
      }
      a = fmaxf(a, 0.f);
      pw2_s[p * CH2 + c] = fmaf(a, sc, sh);
    }
    __syncthreads();
    if (t < CH2) {
      float m = pw2_s[t];
      for (int p = 1; p < VPTS; ++p) m = fmaxf(m, pw2_s[p * CH2 + t]);
      agg2_s[t] = m;
    }
    __syncthreads();
    if (t < 2 * CH2) {
      float vm = -INFINITY;
      if (t < CH2) {
        for (int p = 0; p < VPTS; ++p) vm = fmaxf(vm, pw2_s[p * CH2 + t] * mask_s[p]);
      } else {
        float a = agg2_s[t - CH2];
        for (int p = 0; p < VPTS; ++p) vm = fmaxf(vm, a * mask_s[p]);
      }
      int4 cc = *reinterpret_cast<const int4*>(coord + (size_t)k * 4);
      long vox = ((long)(cc.x * DD + cc.y) * HHH + cc.z) * WWW + cc.w;
      atomicAdd(&out[vox * (2 * CH2) + t], vm);
    }
  }
}

extern "C" void kernel_launch(void* const* d_in, const int* in_sizes, int n_in,
                              void* d_out, int out_size, void* d_ws, size_t ws_size,
                              hipStream_t stream) {
  const float* feat = (const float*)d_in[0];
  const int* coord  = (const int*)d_in[1];
  const float* w1  = (const float*)d_in[3];
  const float* b1  = (const float*)d_in[4];
  const float* g1  = (const float*)d_in[5];
  const float* be1 = (const float*)d_in[6];
  const float* w2  = (const float*)d_in[7];
  const float* b2  = (const float*)d_in[8];
  const float* g2  = (const float*)d_in[9];
  const float* be2 = (const float*)d_in[10];
  float* out = (float*)d_out;
  float* ws = (float*)d_ws;

  int K = in_sizes[0] / (VPTS * CIN1);
  int KP = K * VPTS;
  float invN = 1.f / (float)KP;

  float* red1p = ws;          // 256
  float* red2p = ws + 256;    // 1024
  float* fb    = ws + 1280;   // 320 (fallback stats area)
  float* E1buf = ws + 2048;
  float* E2buf = E1buf + (size_t)64 * K;
  float* FLbuf = E2buf + (size_t)64 * K;

  size_t need_bytes = (2048 + (size_t)K * 129) * sizeof(float);

  // Full-rate rocclr fills (6.6-6.8 TB/s measured) for output + ws stats.
  hipMemsetAsync(out, 0, (size_t)out_size * sizeof(float), stream);
  hipMemsetAsync(ws, 0, 1600 * sizeof(float), stream);

  if (ws_size >= need_bytes) {
    k_stats1<<<512, 256, 0, stream>>>(feat, w1, b1, red1p, KP);
    k_heavy<<<2048, 256, 0, stream>>>(feat, w1, b1, g1, be1, red1p,
                                      w2, b2, g2, red2p, E1buf, E2buf, FLbuf,
                                      K, invN);
    k_scatter<<<(K + 1) / 2, 256, 0, stream>>>(E1buf, E2buf, FLbuf, red2p,
                                               g2, be2, coord, out, K, invN);
  } else {
    float* red1  = fb;
    float* scsh1 = fb + 32;
    float* red2  = fb + 64;
    float* scsh2 = fb + 192;
    k_stats1_fb<<<512, 256, 0, stream>>>(feat, w1, b1, red1, KP);
    k_finalize<<<1, 64, 0, stream>>>(red1, g1, be1, scsh1, CH1, invN);
    k_stats2_old<<<1024, 256, 0, stream>>>(feat, w1, b1, scsh1, w2, b2, red2, K);
    k_finalize<<<1, 64, 0, stream>>>(red2, g2, be2, scsh2, CH2, invN);
    k_final_old<<<2048, 256, 0, stream>>>(feat, w1, b1, scsh1, w2, b2, scsh2,
                                          coord, out, K);
  }
}